// Round 11
// baseline (156.953 us; speedup 1.0000x reference)
//
#include <hip/hip_runtime.h>
#include <hip/hip_bf16.h>

#define BATCH 4
#define SEQ   2048
#define DM    512
#define NH    8
#define HD    64
#define PART  (BATCH*NH*SEQ*HD)   /* 4,194,304 = M*DM */
#define QSCALE 0.18033688f        /* (1/sqrt(64)) * log2(e) : folded into Q */

typedef unsigned short u16;
typedef unsigned int   u32;
typedef __bf16 bf16x8 __attribute__((ext_vector_type(8)));
typedef float  f32x4  __attribute__((ext_vector_type(4)));

__device__ __forceinline__ u16 f2bf(float f) {
    union { float f; u32 u; } v; v.f = f;
    u32 r = v.u + 0x7fffu + ((v.u >> 16) & 1u);   // RNE
    return (u16)(r >> 16);
}

// async global->LDS, 16B per lane; LDS dest = uniform base + lane*16
__device__ __forceinline__ void glds16(const u16* g, u16* lds) {
    __builtin_amdgcn_global_load_lds(
        (const __attribute__((address_space(1))) void*)g,
        (__attribute__((address_space(3))) void*)lds, 16, 0, 0);
}

// ---------------------------------------------------------------------------
// prep: z=0 -> f32->bf16 convert of x (512 blocks, grid-stride)
//       z=1 -> transpose w_qkv (192 blocks)   z=2 -> transpose w_out (64)
// ---------------------------------------------------------------------------
__global__ __launch_bounds__(256) void prep_k(
    const float* __restrict__ x, u16* __restrict__ xb,
    const float* __restrict__ w_qkv, u16* __restrict__ t_qkv,
    const float* __restrict__ w_out, u16* __restrict__ t_out)
{
    __shared__ u16 Ts[64][72];
    const int z = blockIdx.z, bx = blockIdx.x, t = threadIdx.x;

    if (z == 0) {
        const int n8 = PART / 8;
        for (int i = bx * 256 + t; i < n8; i += 512 * 256) {
            float4 a = *(const float4*)(x + (size_t)i * 8);
            float4 b = *(const float4*)(x + (size_t)i * 8 + 4);
            union { uint4 v; u16 s[8]; } o;
            o.s[0] = f2bf(a.x); o.s[1] = f2bf(a.y);
            o.s[2] = f2bf(a.z); o.s[3] = f2bf(a.w);
            o.s[4] = f2bf(b.x); o.s[5] = f2bf(b.y);
            o.s[6] = f2bf(b.z); o.s[7] = f2bf(b.w);
            *(uint4*)(xb + (size_t)i * 8) = o.v;
        }
        return;
    }
    const int N = (z == 1) ? 3 * DM : DM;
    const int ntiles = N / 64;
    if (bx >= ntiles * 8) return;
    const float* W = (z == 1) ? w_qkv : w_out;
    u16* Wt = (z == 1) ? t_qkv : t_out;
    const int n0 = (bx % ntiles) * 64, k0 = (bx / ntiles) * 64;

    #pragma unroll
    for (int l = 0; l < 4; ++l) {
        int idx = l * 1024 + t * 4;
        int r = idx >> 6, c = idx & 63;
        float4 v = *(const float4*)(W + (size_t)(k0 + r) * N + n0 + c);
        Ts[c + 0][r] = f2bf(v.x);
        Ts[c + 1][r] = f2bf(v.y);
        Ts[c + 2][r] = f2bf(v.z);
        Ts[c + 3][r] = f2bf(v.w);
    }
    __syncthreads();
    #pragma unroll
    for (int l = 0; l < 2; ++l) {
        int idx = l * 256 + t;
        int row = idx >> 3, ch = idx & 7;
        *(uint4*)(Wt + (size_t)(n0 + row) * DM + k0 + ch * 8) =
            *(const uint4*)(&Ts[row][ch * 8]);
    }
}

// ---------------------------------------------------------------------------
// GEMM: C(M,N) = A(M,K)bf16 @ Bt(N,K)^T bf16 + bias(N)f32.
// Double-buffered LDS, one barrier per K-step.
// MODE 0: BM=128; coalesced epilogue via LDS transpose:
//         Q (prescaled) | K -> (B,H,S,HD); V -> V^T (B,H,HD,S).
// MODE 1: BM=64 (512 blocks, 2/CU); row-major f32 store.
// ---------------------------------------------------------------------------
template<int MODE>
__global__ __launch_bounds__(256) void gemm_k(
    const u16* __restrict__ A, const u16* __restrict__ Bt,
    const float* __restrict__ bias, void* __restrict__ outv,
    int M, int N, int K)
{
    constexpr int BM = (MODE == 1) ? 64 : 128;
    constexpr int NI = (MODE == 1) ? 2 : 4;

    __shared__ __align__(16) u16 As[2][BM * 32];
    __shared__ __align__(16) u16 Bs[2][128 * 32];
    __shared__ __align__(16) u16 epi[128 * 72];   // MODE 0 epilogue staging

    const int tid  = threadIdx.x;
    const int bm0  = blockIdx.x * BM;
    const int bn0  = blockIdx.y * 128;
    const int wave = tid >> 6, lane = tid & 63;
    const int l16  = lane & 15, quad = lane >> 4;
    const int wr   = (MODE == 1) ? 0 : (wave & 1) * 64;
    const int wc   = (MODE == 1) ? wave * 32 : (wave >> 1) * 64;

    const int srow = (lane >> 2);            // 0..15
    const int scol = (lane & 3) * 8;         // 0,8,16,24
    const int arow = (MODE == 1) ? (wave * 16) : (wave * 32);
    const u16* Ag = A + (size_t)(bm0 + arow + srow) * K + scol;
    const u16* Bg = Bt + (size_t)(bn0 + wave * 32 + srow) * K + scol;
    const int wofsA = arow * 32;
    const int wofsB = (wave * 32) * 32;

    f32x4 acc[4][NI];
    #pragma unroll
    for (int i = 0; i < 4; ++i)
        #pragma unroll
        for (int j = 0; j < NI; ++j)
            acc[i][j] = (f32x4){0.f, 0.f, 0.f, 0.f};

    glds16(Ag, &As[0][wofsA]);
    if (MODE == 0) glds16(Ag + (size_t)16 * K, &As[0][wofsA + 16 * 32]);
    glds16(Bg,                  &Bs[0][wofsB]);
    glds16(Bg + (size_t)16 * K, &Bs[0][wofsB + 16 * 32]);
    __syncthreads();

    const int NIT = K >> 5;
    for (int it = 0; it < NIT; ++it) {
        const int cur = it & 1;
        if (it + 1 < NIT) {
            const int nx = cur ^ 1;
            const int k0 = (it + 1) << 5;
            glds16(Ag + k0, &As[nx][wofsA]);
            if (MODE == 0) glds16(Ag + k0 + (size_t)16 * K, &As[nx][wofsA + 16 * 32]);
            glds16(Bg + k0,                  &Bs[nx][wofsB]);
            glds16(Bg + k0 + (size_t)16 * K, &Bs[nx][wofsB + 16 * 32]);
        }

        bf16x8 af[4], bfr[NI];
        #pragma unroll
        for (int mi = 0; mi < 4; ++mi)
            af[mi] = *(const bf16x8*)(&As[cur][(wr + mi * 16 + l16) * 32 + quad * 8]);
        #pragma unroll
        for (int ni = 0; ni < NI; ++ni)
            bfr[ni] = *(const bf16x8*)(&Bs[cur][(wc + ni * 16 + l16) * 32 + quad * 8]);
        #pragma unroll
        for (int mi = 0; mi < 4; ++mi)
            #pragma unroll
            for (int ni = 0; ni < NI; ++ni)
                acc[mi][ni] = __builtin_amdgcn_mfma_f32_16x16x32_bf16(
                    af[mi], bfr[ni], acc[mi][ni], 0, 0, 0);
        __syncthreads();
    }

    if (MODE == 1) {
        #pragma unroll
        for (int mi = 0; mi < 4; ++mi)
            #pragma unroll
            for (int ni = 0; ni < NI; ++ni) {
                int col = bn0 + wc + ni * 16 + l16;
                float bv = bias[col];
                int row0 = bm0 + wr + mi * 16 + quad * 4;
                #pragma unroll
                for (int reg = 0; reg < 4; ++reg)
                    ((float*)outv)[(size_t)(row0 + reg) * N + col] =
                        acc[mi][ni][reg] + bv;
            }
    } else {
        // Coalesced scatter via LDS transpose, one 64-col half at a time.
        u16* ws = (u16*)outv;
        const int part = bn0 >> 9;            // uniform per block
        const int h0   = (bn0 & 511) >> 6;    // head of half 0
        const int bq   = bm0 >> 11, s0 = bm0 & 2047;

        #pragma unroll
        for (int hh = 0; hh < 2; ++hh) {
            if ((wave >> 1) == hh) {          // writer waves for this half
                #pragma unroll
                for (int mi = 0; mi < 4; ++mi)
                    #pragma unroll
                    for (int ni = 0; ni < 4; ++ni) {
                        int ce  = ni * 16 + l16;              // 0..63 in half
                        float bv = bias[bn0 + wc + ce - 0];   // wc==hh*64
                        int row0 = wr + mi * 16 + quad * 4;   // 0..127 local
                        if (part < 2) {
                            float scl = (part == 0) ? QSCALE : 1.0f;
                            #pragma unroll
                            for (int reg = 0; reg < 4; ++reg)
                                epi[(row0 + reg) * 72 + ce] =
                                    f2bf((acc[mi][ni][reg] + bv) * scl);
                        } else {
                            union { u16 q[4]; uint2 u; } pk;
                            #pragma unroll
                            for (int reg = 0; reg < 4; ++reg)
                                pk.q[reg] = f2bf(acc[mi][ni][reg] + bv);
                            *(uint2*)(&epi[ce * 144 + row0]) = pk.u;  // [e][s]
                        }
                    }
            }
            __syncthreads();
            if (part < 2) {
                #pragma unroll
                for (int l = 0; l < 4; ++l) {
                    int idx = l * 256 + tid;
                    int r = idx >> 3, e8 = (idx & 7) * 8;
                    uint4 v = *(const uint4*)(&epi[r * 72 + e8]);
                    *(uint4*)(ws + (size_t)part * PART +
                              (((size_t)(bq * NH + h0 + hh) * SEQ) + s0 + r) * HD
                              + e8) = v;
                }
            } else {
                #pragma unroll
                for (int l = 0; l < 4; ++l) {
                    int idx = l * 256 + tid;
                    int e = idx >> 4, sc = (idx & 15) * 8;
                    uint4 v = *(const uint4*)(&epi[e * 144 + sc]);
                    *(uint4*)(ws + (size_t)2 * PART +
                              (((size_t)(bq * NH + h0 + hh) * HD) + e) * SEQ
                              + s0 + sc) = v;
                }
            }
            __syncthreads();
        }
    }
}

// ---------------------------------------------------------------------------
// Causal flash attention, streaming softmax (exp2; scale folded into Q).
// Q,K: (B,H,S,HD) bf16. Vt: (B,H,HD,S) bf16. Out: (B,S,H,HD) bf16.
// SMALL-BLOCK / HIGH-TLP version: block = 128 threads (2 waves), 32 q-rows.
// Grid (32 bh x 32 pairs) = 1024 blocks = 4 blocks/CU = 16 waves/CU
// (4 waves/SIMD from 4 INDEPENDENT blocks -> barrier stalls of one block are
// hidden by the other three; r10's 2-block lockstep was the stall).
// Pair (t, 63-t) of 32-row q-tiles: 32-33 windows per block (uniform).
// Inner loop = r9 structure: K/V glds16 double-buffered XOR-swizzled LDS,
// one barrier per window, P wave-private.
// ---------------------------------------------------------------------------
__global__ __launch_bounds__(128) void attn_k(
    const u16* __restrict__ Q, const u16* __restrict__ K,
    const u16* __restrict__ Vt, u16* __restrict__ O)
{
    __shared__ __align__(16) u16 KsB[2][64 * 64];   // [kv][d], chunk-swizzled
    __shared__ __align__(16) u16 VtB[2][64 * 64];   // [d][kv], chunk-swizzled
    __shared__ __align__(16) u16 Ps[32][72];        // Q stage, then P (wave-priv)

    const int bh = blockIdx.x;
    const int pr = blockIdx.y;                 // 0..31
    const int tid = threadIdx.x, wave = tid >> 6, lane = tid & 63;
    const int l16 = lane & 15, quad = lane >> 4;
    const size_t baseK = (size_t)bh * SEQ * HD;
    const size_t baseV = (size_t)bh * HD * SEQ;
    const int b = bh >> 3, h = bh & 7;
    const int row32 = wave * 16 + quad * 4;    // q-row in 32-row tile

    // glds lane source addressing (XOR chunk swizzle at the source)
    const int sub = lane >> 3;                 // 0..7
    const int lcx = (lane & 7) ^ sub;          // logical 16B chunk for this lane
    // wave w stages tile rows w*32 .. w*32+31 (4 glds of 8 rows each)
    const u16* kg = K  + baseK + (size_t)((wave * 32 + sub) * 64)   + lcx * 8;
    const u16* vg = Vt + baseV + (size_t)((wave * 32 + sub) * 2048) + lcx * 8;
    u16* ksd = &KsB[0][wave * 2048];
    u16* vtd = &VtB[0][wave * 2048];

    #pragma unroll
    for (int phase = 0; phase < 2; ++phase) {
        const int t = phase ? pr : (63 - pr);      // 32-row q-tile index
        const int nkv = (t >> 1);                  // last kv tile index
        const size_t baseQ = baseK + (size_t)t * 32 * HD;

        __syncthreads();   // prior phase reads done before Ps/KsB/VtB reuse

        // ---- stage Q (32x64) into Ps ----
        #pragma unroll
        for (int r = 0; r < 2; ++r) {
            int idx = r * 128 + tid;
            int row = idx >> 3, c8 = (idx & 7) << 3;
            *(uint4*)(&Ps[row][c8]) = *(const uint4*)(Q + baseQ + row * 64 + c8);
        }
        __syncthreads();
        bf16x8 qf[2];
        #pragma unroll
        for (int d0 = 0; d0 < 2; ++d0)
            qf[d0] = *(const bf16x8*)(&Ps[wave * 16 + l16][d0 * 32 + quad * 8]);

        // prologue: stage kt=0 into buffer 0 (each wave: 4 K + 4 V glds)
        #pragma unroll
        for (int i = 0; i < 4; ++i) {
            glds16(kg + (size_t)i * 8 * 64,   ksd + i * 512);
            glds16(vg + (size_t)i * 8 * 2048, vtd + i * 512);
        }
        __syncthreads();   // qf reads done block-wide + buf0 landed

        float l_part[4] = {0.f, 0.f, 0.f, 0.f};
        f32x4 o_acc[4];
        #pragma unroll
        for (int i = 0; i < 4; ++i) o_acc[i] = (f32x4){0.f, 0.f, 0.f, 0.f};

        for (int kt = 0; kt <= nkv; ++kt) {
            const int cur = kt & 1;
            if (kt < nkv) {   // prefetch kt+1
                const int nx = (cur ^ 1) * 4096;
                #pragma unroll
                for (int i = 0; i < 4; ++i) {
                    glds16(kg + (size_t)(kt + 1) * 4096 + (size_t)i * 8 * 64,
                           ksd + nx + i * 512);
                    glds16(vg + (size_t)(kt + 1) * 64 + (size_t)i * 8 * 2048,
                           vtd + nx + i * 512);
                }
            }

            // K and V fragments up front (ds latency overlaps MFMA+exp)
            bf16x8 kf[2][4], vf[2][4];
            #pragma unroll
            for (int d0 = 0; d0 < 2; ++d0)
                #pragma unroll
                for (int nt = 0; nt < 4; ++nt) {
                    int pc = (d0 * 4 + quad) ^ (l16 & 7);
                    kf[d0][nt] = *(const bf16x8*)
                        (&KsB[cur][(nt * 16 + l16) * 64 + pc * 8]);
                    vf[d0][nt] = *(const bf16x8*)
                        (&VtB[cur][(nt * 16 + l16) * 64 + pc * 8]);
                }

            f32x4 s[4];
            #pragma unroll
            for (int nt = 0; nt < 4; ++nt) s[nt] = (f32x4){0.f, 0.f, 0.f, 0.f};
            #pragma unroll
            for (int d0 = 0; d0 < 2; ++d0)
                #pragma unroll
                for (int nt = 0; nt < 4; ++nt)
                    s[nt] = __builtin_amdgcn_mfma_f32_16x16x32_bf16(
                        qf[d0], kf[d0][nt], s[nt], 0, 0, 0);

            // causal mask on the last kv tile: global col kt*64+cl vs
            // global row t*32+row32+reg  ->  cl > (t&1)*32 + row32 + reg
            const bool diag = (kt == nkv);
            const int rbase = (t & 1) * 32 + row32;
            #pragma unroll
            for (int nt = 0; nt < 4; ++nt) {
                int cl = nt * 16 + l16;
                float p[4];
                #pragma unroll
                for (int reg = 0; reg < 4; ++reg) {
                    p[reg] = __builtin_amdgcn_exp2f(s[nt][reg]);
                    if (diag && cl > rbase + reg) p[reg] = 0.f;
                    l_part[reg] += p[reg];
                }
                union { __hip_bfloat162 hh2; u16 s2[2]; } pk01, pk23;
                pk01.hh2 = __float22bfloat162_rn(float2{p[0], p[1]});
                pk23.hh2 = __float22bfloat162_rn(float2{p[2], p[3]});
                Ps[row32 + 0][cl] = pk01.s2[0];
                Ps[row32 + 1][cl] = pk01.s2[1];
                Ps[row32 + 2][cl] = pk23.s2[0];
                Ps[row32 + 3][cl] = pk23.s2[1];
            }

            // PV: Ps rows wave-private; lgkmcnt orders write->read
            #pragma unroll
            for (int k0 = 0; k0 < 2; ++k0) {
                bf16x8 ap = *(const bf16x8*)
                    (&Ps[wave * 16 + l16][k0 * 32 + quad * 8]);
                #pragma unroll
                for (int dt = 0; dt < 4; ++dt)
                    o_acc[dt] = __builtin_amdgcn_mfma_f32_16x16x32_bf16(
                        ap, vf[k0][dt], o_acc[dt], 0, 0, 0);
            }
            __syncthreads();   // all waves done with buf[cur]; prefetch drained
        }

        // ---- reduce l across the 16 lanes sharing each q-row; store O ----
        float l_i[4];
        #pragma unroll
        for (int reg = 0; reg < 4; ++reg) {
            float l = l_part[reg];
            #pragma unroll
            for (int off = 1; off < 16; off <<= 1)
                l += __shfl_xor(l, off);
            l_i[reg] = l;
        }
        #pragma unroll
        for (int dt = 0; dt < 4; ++dt) {
            #pragma unroll
            for (int reg = 0; reg < 4; ++reg) {
                int srow = t * 32 + row32 + reg;
                float v = o_acc[dt][reg] / l_i[reg];
                size_t idx = (((size_t)(b * SEQ + srow)) * NH + h) * HD
                             + dt * 16 + l16;
                O[idx] = f2bf(v);
            }
        }
    }
}

extern "C" void kernel_launch(void* const* d_in, const int* in_sizes, int n_in,
                              void* d_out, int out_size, void* d_ws, size_t ws_size,
                              hipStream_t stream) {
    const float* x     = (const float*)d_in[0];
    const float* w_qkv = (const float*)d_in[1];
    const float* b_qkv = (const float*)d_in[2];
    const float* w_out = (const float*)d_in[3];
    const float* b_out = (const float*)d_in[4];

    u16* qkv    = (u16*)d_ws;                       // Q | K | V^T, each PART
    u16* attn   = qkv + (size_t)3 * PART;           // PART bf16 (B,S,H,HD)
    u16* xb     = attn + (size_t)PART;              // PART bf16 (x converted)
    u16* wt_qkv = xb + (size_t)PART;                // 1536*512 bf16
    u16* wt_out = wt_qkv + (size_t)(3 * DM) * DM;   // 512*512 bf16

    const int M = BATCH * SEQ;                      // 8192

    prep_k<<<dim3(512, 1, 3), 256, 0, stream>>>(x, xb, w_qkv, wt_qkv,
                                                w_out, wt_out);

    dim3 g1(M / 128, (3 * DM) / 128);               // 64 x 12
    gemm_k<0><<<g1, 256, 0, stream>>>(xb, wt_qkv, b_qkv, qkv, M, 3 * DM, DM);

    dim3 g2(BATCH * NH, 32);                        // 1024 blocks, 4/CU
    attn_k<<<g2, 128, 0, stream>>>(qkv, qkv + PART, qkv + 2 * (size_t)PART, attn);

    dim3 g3(M / 64, DM / 128);                      // 128 x 4 = 512 blocks
    gemm_k<1><<<g3, 256, 0, stream>>>(attn, wt_out, b_out, (float*)d_out, M, DM, DM);
}

// Round 12
// 154.409 us; speedup vs baseline: 1.0165x; 1.0165x over previous
//
#include <hip/hip_runtime.h>
#include <hip/hip_bf16.h>

#define BATCH 4
#define SEQ   2048
#define DM    512
#define NH    8
#define HD    64
#define PART  (BATCH*NH*SEQ*HD)   /* 4,194,304 = M*DM */
#define QSCALE 0.18033688f        /* (1/sqrt(64)) * log2(e) : folded into Q */

typedef unsigned short u16;
typedef unsigned int   u32;
typedef __bf16 bf16x8 __attribute__((ext_vector_type(8)));
typedef float  f32x4  __attribute__((ext_vector_type(4)));

__device__ __forceinline__ u16 f2bf(float f) {
    union { float f; u32 u; } v; v.f = f;
    u32 r = v.u + 0x7fffu + ((v.u >> 16) & 1u);   // RNE
    return (u16)(r >> 16);
}
__device__ __forceinline__ u32 pk2(float a, float b) {   // packed cvt (1 VALU)
    union { __hip_bfloat162 h; u32 u; } x;
    x.h = __float22bfloat162_rn(float2{a, b});
    return x.u;
}

// async global->LDS, 16B per lane; LDS dest = uniform base + lane*16
__device__ __forceinline__ void glds16(const u16* g, u16* lds) {
    __builtin_amdgcn_global_load_lds(
        (const __attribute__((address_space(1))) void*)g,
        (__attribute__((address_space(3))) void*)lds, 16, 0, 0);
}

// ---------------------------------------------------------------------------
// prep: weight transposes only (x-convert is fused into gemm_qkv_k).
// bx<192: w_qkv (N=1536) tiles; bx>=192: w_out (N=512) tiles. K=512.
// ---------------------------------------------------------------------------
__global__ __launch_bounds__(256) void prep_k(
    const float* __restrict__ w_qkv, u16* __restrict__ t_qkv,
    const float* __restrict__ w_out, u16* __restrict__ t_out)
{
    __shared__ u16 Ts[64][72];
    const int bx = blockIdx.x, t = threadIdx.x;
    const float* W; u16* Wt; int N, n0, k0;
    if (bx < 192) { W = w_qkv; Wt = t_qkv; N = 3 * DM;
                    n0 = (bx % 24) * 64; k0 = (bx / 24) * 64; }
    else          { int i = bx - 192; W = w_out; Wt = t_out; N = DM;
                    n0 = (i % 8) * 64;  k0 = (i / 8) * 64; }

    #pragma unroll
    for (int l = 0; l < 4; ++l) {
        int idx = l * 1024 + t * 4;
        int r = idx >> 6, c = idx & 63;
        float4 v = *(const float4*)(W + (size_t)(k0 + r) * N + n0 + c);
        Ts[c + 0][r] = f2bf(v.x);
        Ts[c + 1][r] = f2bf(v.y);
        Ts[c + 2][r] = f2bf(v.z);
        Ts[c + 3][r] = f2bf(v.w);
    }
    __syncthreads();
    #pragma unroll
    for (int l = 0; l < 2; ++l) {
        int idx = l * 256 + t;
        int row = idx >> 3, ch = idx & 7;
        *(uint4*)(Wt + (size_t)(n0 + row) * DM + k0 + ch * 8) =
            *(const uint4*)(&Ts[row][ch * 8]);
    }
}

// ---------------------------------------------------------------------------
// QKV GEMM: C(8192,1536) = x(8192,512)f32 @ Wt^T + bias. FUSED f32->bf16
// A-staging (register-double-buffered loads, packed cvt, ds_write); B via
// glds16 double-buffer. Coalesced epilogue via LDS transpose:
// Q (prescaled) | K -> (B,H,S,HD); V -> V^T (B,H,HD,S).
// ---------------------------------------------------------------------------
__global__ __launch_bounds__(256) void gemm_qkv_k(
    const float* __restrict__ A, const u16* __restrict__ Bt,
    const float* __restrict__ bias, u16* __restrict__ ws)
{
    constexpr int K = DM;                    // 512
    __shared__ __align__(16) u16 As[2][128 * 32];
    __shared__ __align__(16) u16 Bs[2][128 * 32];
    __shared__ __align__(16) u16 epi[128 * 72];

    const int tid  = threadIdx.x;
    const int bm0  = blockIdx.x * 128;
    const int bn0  = blockIdx.y * 128;
    const int wave = tid >> 6, lane = tid & 63;
    const int l16  = lane & 15, quad = lane >> 4;
    const int wr   = (wave & 1) * 64;
    const int wc   = (wave >> 1) * 64;

    // ---- A staging (f32 source): thread -> row tid>>1, 16-col half ----
    const int arow = tid >> 1, acol = (tid & 1) * 16;
    const float* Ax = A + (size_t)(bm0 + arow) * K + acol;
    f32x4 ar[4];

    // ---- B staging via glds ----
    const int srow = (lane >> 2), scol = (lane & 3) * 8;
    const u16* Bg = Bt + (size_t)(bn0 + wave * 32 + srow) * K + scol;
    const int wofsB = (wave * 32) * 32;

    f32x4 acc[4][4];
    #pragma unroll
    for (int i = 0; i < 4; ++i)
        #pragma unroll
        for (int j = 0; j < 4; ++j)
            acc[i][j] = (f32x4){0.f, 0.f, 0.f, 0.f};

    // prologue: stage k0=0
    #pragma unroll
    for (int i = 0; i < 4; ++i)
        ar[i] = *(const f32x4*)(Ax + i * 4);
    {
        uint4 w0 = {pk2(ar[0][0], ar[0][1]), pk2(ar[0][2], ar[0][3]),
                    pk2(ar[1][0], ar[1][1]), pk2(ar[1][2], ar[1][3])};
        uint4 w1 = {pk2(ar[2][0], ar[2][1]), pk2(ar[2][2], ar[2][3]),
                    pk2(ar[3][0], ar[3][1]), pk2(ar[3][2], ar[3][3])};
        *(uint4*)(&As[0][arow * 32 + acol])     = w0;
        *(uint4*)(&As[0][arow * 32 + acol + 8]) = w1;
    }
    glds16(Bg,                  &Bs[0][wofsB]);
    glds16(Bg + (size_t)16 * K, &Bs[0][wofsB + 16 * 32]);
    __syncthreads();

    const int NIT = K >> 5;                  // 16
    for (int it = 0; it < NIT; ++it) {
        const int cur = it & 1, nx = cur ^ 1;
        if (it + 1 < NIT) {
            const int k0 = (it + 1) << 5;
            #pragma unroll
            for (int i = 0; i < 4; ++i)
                ar[i] = *(const f32x4*)(Ax + k0 + i * 4);
            glds16(Bg + k0,                  &Bs[nx][wofsB]);
            glds16(Bg + k0 + (size_t)16 * K, &Bs[nx][wofsB + 16 * 32]);
        }

        bf16x8 af[4], bfr[4];
        #pragma unroll
        for (int mi = 0; mi < 4; ++mi)
            af[mi] = *(const bf16x8*)(&As[cur][(wr + mi * 16 + l16) * 32 + quad * 8]);
        #pragma unroll
        for (int ni = 0; ni < 4; ++ni)
            bfr[ni] = *(const bf16x8*)(&Bs[cur][(wc + ni * 16 + l16) * 32 + quad * 8]);
        #pragma unroll
        for (int mi = 0; mi < 4; ++mi)
            #pragma unroll
            for (int ni = 0; ni < 4; ++ni)
                acc[mi][ni] = __builtin_amdgcn_mfma_f32_16x16x32_bf16(
                    af[mi], bfr[ni], acc[mi][ni], 0, 0, 0);

        if (it + 1 < NIT) {
            uint4 w0 = {pk2(ar[0][0], ar[0][1]), pk2(ar[0][2], ar[0][3]),
                        pk2(ar[1][0], ar[1][1]), pk2(ar[1][2], ar[1][3])};
            uint4 w1 = {pk2(ar[2][0], ar[2][1]), pk2(ar[2][2], ar[2][3]),
                        pk2(ar[3][0], ar[3][1]), pk2(ar[3][2], ar[3][3])};
            *(uint4*)(&As[nx][arow * 32 + acol])     = w0;
            *(uint4*)(&As[nx][arow * 32 + acol + 8]) = w1;
        }
        __syncthreads();
    }

    // ---- coalesced epilogue via LDS transpose, one 64-col half at a time ----
    const int part = bn0 >> 9;               // 0=Q 1=K 2=V (uniform per block)
    const int h0   = (bn0 & 511) >> 6;
    const int bq   = bm0 >> 11, s0 = bm0 & 2047;

    #pragma unroll
    for (int hh = 0; hh < 2; ++hh) {
        if ((wave >> 1) == hh) {             // writer waves for this half
            #pragma unroll
            for (int mi = 0; mi < 4; ++mi)
                #pragma unroll
                for (int ni = 0; ni < 4; ++ni) {
                    int ce  = ni * 16 + l16;
                    float bv = bias[bn0 + hh * 64 + ce];
                    int row0 = wr + mi * 16 + quad * 4;
                    if (part < 2) {
                        float scl = (part == 0) ? QSCALE : 1.0f;
                        #pragma unroll
                        for (int reg = 0; reg < 4; ++reg)
                            epi[(row0 + reg) * 72 + ce] =
                                f2bf((acc[mi][ni][reg] + bv) * scl);
                    } else {
                        union { u16 q[4]; uint2 u; } pk;
                        #pragma unroll
                        for (int reg = 0; reg < 4; ++reg)
                            pk.q[reg] = f2bf(acc[mi][ni][reg] + bv);
                        *(uint2*)(&epi[ce * 144 + row0]) = pk.u;  // [e][s]
                    }
                }
        }
        __syncthreads();
        if (part < 2) {
            #pragma unroll
            for (int l = 0; l < 4; ++l) {
                int idx = l * 256 + tid;
                int r = idx >> 3, e8 = (idx & 7) * 8;
                uint4 v = *(const uint4*)(&epi[r * 72 + e8]);
                *(uint4*)(ws + (size_t)part * PART +
                          (((size_t)(bq * NH + h0 + hh) * SEQ) + s0 + r) * HD
                          + e8) = v;
            }
        } else {
            #pragma unroll
            for (int l = 0; l < 4; ++l) {
                int idx = l * 256 + tid;
                int e = idx >> 4, sc = (idx & 15) * 8;
                uint4 v = *(const uint4*)(&epi[e * 144 + sc]);
                *(uint4*)(ws + (size_t)2 * PART +
                          (((size_t)(bq * NH + h0 + hh) * HD) + e) * SEQ
                          + s0 + sc) = v;
            }
        }
        __syncthreads();
    }
}

// ---------------------------------------------------------------------------
// Out-proj GEMM: C(8192,512)f32 = attn(8192,512)bf16 @ Wt^T + bias.
// BM=64 (512 blocks, 2/CU), glds double-buffer, one barrier per K-step.
// ---------------------------------------------------------------------------
__global__ __launch_bounds__(256) void gemm_out_k(
    const u16* __restrict__ A, const u16* __restrict__ Bt,
    const float* __restrict__ bias, float* __restrict__ out)
{
    constexpr int K = DM, N = DM;
    __shared__ __align__(16) u16 As[2][64 * 32];
    __shared__ __align__(16) u16 Bs[2][128 * 32];

    const int tid  = threadIdx.x;
    const int bm0  = blockIdx.x * 64;
    const int bn0  = blockIdx.y * 128;
    const int wave = tid >> 6, lane = tid & 63;
    const int l16  = lane & 15, quad = lane >> 4;
    const int wc   = wave * 32;

    const int srow = (lane >> 2), scol = (lane & 3) * 8;
    const u16* Ag = A + (size_t)(bm0 + wave * 16 + srow) * K + scol;
    const u16* Bg = Bt + (size_t)(bn0 + wave * 32 + srow) * K + scol;
    const int wofsA = (wave * 16) * 32;
    const int wofsB = (wave * 32) * 32;

    f32x4 acc[4][2];
    #pragma unroll
    for (int i = 0; i < 4; ++i)
        #pragma unroll
        for (int j = 0; j < 2; ++j)
            acc[i][j] = (f32x4){0.f, 0.f, 0.f, 0.f};

    glds16(Ag,                  &As[0][wofsA]);
    glds16(Bg,                  &Bs[0][wofsB]);
    glds16(Bg + (size_t)16 * K, &Bs[0][wofsB + 16 * 32]);
    __syncthreads();

    const int NIT = K >> 5;
    for (int it = 0; it < NIT; ++it) {
        const int cur = it & 1;
        if (it + 1 < NIT) {
            const int nx = cur ^ 1;
            const int k0 = (it + 1) << 5;
            glds16(Ag + k0,                  &As[nx][wofsA]);
            glds16(Bg + k0,                  &Bs[nx][wofsB]);
            glds16(Bg + k0 + (size_t)16 * K, &Bs[nx][wofsB + 16 * 32]);
        }

        bf16x8 af[4], bfr[2];
        #pragma unroll
        for (int mi = 0; mi < 4; ++mi)
            af[mi] = *(const bf16x8*)(&As[cur][(mi * 16 + l16) * 32 + quad * 8]);
        #pragma unroll
        for (int ni = 0; ni < 2; ++ni)
            bfr[ni] = *(const bf16x8*)(&Bs[cur][(wc + ni * 16 + l16) * 32 + quad * 8]);
        #pragma unroll
        for (int mi = 0; mi < 4; ++mi)
            #pragma unroll
            for (int ni = 0; ni < 2; ++ni)
                acc[mi][ni] = __builtin_amdgcn_mfma_f32_16x16x32_bf16(
                    af[mi], bfr[ni], acc[mi][ni], 0, 0, 0);
        __syncthreads();
    }

    #pragma unroll
    for (int mi = 0; mi < 4; ++mi)
        #pragma unroll
        for (int ni = 0; ni < 2; ++ni) {
            int col = bn0 + wc + ni * 16 + l16;
            float bv = bias[col];
            int row0 = bm0 + mi * 16 + quad * 4;
            #pragma unroll
            for (int reg = 0; reg < 4; ++reg)
                out[(size_t)(row0 + reg) * N + col] = acc[mi][ni][reg] + bv;
        }
}

// ---------------------------------------------------------------------------
// Causal flash attention — EXACT round-9 structure (best measured: 44 µs).
// Q,K: (B,H,S,HD) bf16. Vt: (B,H,HD,S) bf16. Out: (B,S,H,HD) bf16.
// Uniform-work blocks: q-tile pair {31-pair, pair} of 64 rows, 33 windows.
// K/V glds16 into double-buffered XOR-chunk-swizzled LDS; one barrier per
// window; P wave-private in Ps. Grid x=bh (XCD L2-local K/V).
// ---------------------------------------------------------------------------
__global__ __launch_bounds__(256) void attn_k(
    const u16* __restrict__ Q, const u16* __restrict__ K,
    const u16* __restrict__ Vt, u16* __restrict__ O)
{
    __shared__ __align__(16) u16 KsB[2][64 * 64];   // [kv][d], chunk-swizzled
    __shared__ __align__(16) u16 VtB[2][64 * 64];   // [d][kv], chunk-swizzled
    __shared__ __align__(16) u16 Ps[64][72];        // Q stage, then P (wave-priv)

    const int bh = blockIdx.x;
    const int pair = blockIdx.y;               // 0..15
    const int tid = threadIdx.x, wave = tid >> 6, lane = tid & 63;
    const int l16 = lane & 15, quad = lane >> 4;
    const size_t baseK = (size_t)bh * SEQ * HD;
    const size_t baseV = (size_t)bh * HD * SEQ;
    const int b = bh >> 3, h = bh & 7;
    const int row64 = wave * 16 + quad * 4;

    const int sub = lane >> 3;
    const int lcx = (lane & 7) ^ sub;          // XOR chunk swizzle at source
    const u16* kg = K  + baseK + (size_t)((wave * 16 + sub) * 64)   + lcx * 8;
    const u16* vg = Vt + baseV + (size_t)((wave * 16 + sub) * 2048) + lcx * 8;
    u16* ksd = &KsB[0][wave * 1024];
    u16* vtd = &VtB[0][wave * 1024];

    #pragma unroll
    for (int phase = 0; phase < 2; ++phase) {
        const int qt = phase ? pair : (31 - pair);
        const size_t baseQ = baseK + (size_t)qt * 64 * HD;

        __syncthreads();   // prior phase reads done before Ps/KsB/VtB reuse

        #pragma unroll
        for (int r = 0; r < 2; ++r) {
            int chunk = r * 256 + tid;
            int row = chunk >> 3, c8 = (chunk & 7) << 3;
            *(uint4*)(&Ps[row][c8]) = *(const uint4*)(Q + baseQ + row * 64 + c8);
        }
        __syncthreads();
        bf16x8 qf[2];
        #pragma unroll
        for (int d0 = 0; d0 < 2; ++d0)
            qf[d0] = *(const bf16x8*)(&Ps[wave * 16 + l16][d0 * 32 + quad * 8]);

        glds16(kg,            ksd);
        glds16(kg + 8 * 64,   ksd + 512);
        glds16(vg,            vtd);
        glds16(vg + 8 * 2048, vtd + 512);
        __syncthreads();   // qf reads done block-wide + buf0 landed

        float l_part[4] = {0.f, 0.f, 0.f, 0.f};
        f32x4 o_acc[4];
        #pragma unroll
        for (int i = 0; i < 4; ++i) o_acc[i] = (f32x4){0.f, 0.f, 0.f, 0.f};

        for (int kt = 0; kt <= qt; ++kt) {
            const int cur = kt & 1;
            if (kt < qt) {
                const int nx = (cur ^ 1) * 4096;
                glds16(kg + (size_t)(kt + 1) * 4096,          ksd + nx);
                glds16(kg + (size_t)(kt + 1) * 4096 + 8 * 64, ksd + nx + 512);
                glds16(vg + (size_t)(kt + 1) * 64,            vtd + nx);
                glds16(vg + (size_t)(kt + 1) * 64 + 8 * 2048, vtd + nx + 512);
            }

            bf16x8 kf[2][4], vf[2][4];
            #pragma unroll
            for (int d0 = 0; d0 < 2; ++d0)
                #pragma unroll
                for (int nt = 0; nt < 4; ++nt) {
                    int pc = (d0 * 4 + quad) ^ (l16 & 7);
                    kf[d0][nt] = *(const bf16x8*)
                        (&KsB[cur][(nt * 16 + l16) * 64 + pc * 8]);
                    vf[d0][nt] = *(const bf16x8*)
                        (&VtB[cur][(nt * 16 + l16) * 64 + pc * 8]);
                }

            f32x4 s[4];
            #pragma unroll
            for (int nt = 0; nt < 4; ++nt) s[nt] = (f32x4){0.f, 0.f, 0.f, 0.f};
            #pragma unroll
            for (int d0 = 0; d0 < 2; ++d0)
                #pragma unroll
                for (int nt = 0; nt < 4; ++nt)
                    s[nt] = __builtin_amdgcn_mfma_f32_16x16x32_bf16(
                        qf[d0], kf[d0][nt], s[nt], 0, 0, 0);

            const bool diag = (kt == qt);
            #pragma unroll
            for (int nt = 0; nt < 4; ++nt) {
                int cl = nt * 16 + l16;
                float p[4];
                #pragma unroll
                for (int reg = 0; reg < 4; ++reg) {
                    p[reg] = __builtin_amdgcn_exp2f(s[nt][reg]);
                    if (diag && cl > row64 + reg) p[reg] = 0.f;
                    l_part[reg] += p[reg];
                }
                union { __hip_bfloat162 hh2; u16 s2[2]; } pk01, pk23;
                pk01.hh2 = __float22bfloat162_rn(float2{p[0], p[1]});
                pk23.hh2 = __float22bfloat162_rn(float2{p[2], p[3]});
                Ps[row64 + 0][cl] = pk01.s2[0];
                Ps[row64 + 1][cl] = pk01.s2[1];
                Ps[row64 + 2][cl] = pk23.s2[0];
                Ps[row64 + 3][cl] = pk23.s2[1];
            }

            #pragma unroll
            for (int k0 = 0; k0 < 2; ++k0) {
                bf16x8 ap = *(const bf16x8*)
                    (&Ps[wave * 16 + l16][k0 * 32 + quad * 8]);
                #pragma unroll
                for (int dt = 0; dt < 4; ++dt)
                    o_acc[dt] = __builtin_amdgcn_mfma_f32_16x16x32_bf16(
                        ap, vf[k0][dt], o_acc[dt], 0, 0, 0);
            }
            __syncthreads();
        }

        float l_i[4];
        #pragma unroll
        for (int reg = 0; reg < 4; ++reg) {
            float l = l_part[reg];
            #pragma unroll
            for (int off = 1; off < 16; off <<= 1)
                l += __shfl_xor(l, off);
            l_i[reg] = l;
        }
        #pragma unroll
        for (int dt = 0; dt < 4; ++dt) {
            #pragma unroll
            for (int reg = 0; reg < 4; ++reg) {
                int srow = qt * 64 + row64 + reg;
                float v = o_acc[dt][reg] / l_i[reg];
                size_t idx = (((size_t)(b * SEQ + srow)) * NH + h) * HD
                             + dt * 16 + l16;
                O[idx] = f2bf(v);
            }
        }
    }
}

extern "C" void kernel_launch(void* const* d_in, const int* in_sizes, int n_in,
                              void* d_out, int out_size, void* d_ws, size_t ws_size,
                              hipStream_t stream) {
    const float* x     = (const float*)d_in[0];
    const float* w_qkv = (const float*)d_in[1];
    const float* b_qkv = (const float*)d_in[2];
    const float* w_out = (const float*)d_in[3];
    const float* b_out = (const float*)d_in[4];

    u16* qkv    = (u16*)d_ws;                       // Q | K | V^T, each PART
    u16* attn   = qkv + (size_t)3 * PART;           // PART bf16 (B,S,H,HD)
    u16* wt_qkv = attn + (size_t)PART;              // 1536*512 bf16
    u16* wt_out = wt_qkv + (size_t)(3 * DM) * DM;   // 512*512 bf16

    const int M = BATCH * SEQ;                      // 8192

    prep_k<<<256, 256, 0, stream>>>(w_qkv, wt_qkv, w_out, wt_out);

    dim3 g1(M / 128, (3 * DM) / 128);               // 64 x 12
    gemm_qkv_k<<<g1, 256, 0, stream>>>(x, wt_qkv, b_qkv, qkv);

    dim3 g2(BATCH * NH, 16);                        // bh x pair (uniform work)
    attn_k<<<g2, 256, 0, stream>>>(qkv, qkv + PART, qkv + 2 * (size_t)PART, attn);

    dim3 g3(M / 64, DM / 128);                      // 128 x 4 = 512 blocks
    gemm_out_k<<<g3, 256, 0, stream>>>(attn, wt_out, b_out, (float*)d_out);
}